// Round 18
// baseline (214.541 us; speedup 1.0000x reference)
//
#include <hip/hip_runtime.h>
#include <cstdint>
#include <cstddef>

// ---------------------------------------------------------------------------
// GCN: 3 layers, shared graph.
//   - Algebra: out = log_softmax( A^2 (relu(A xW1 + b1) W23) + s*(b2W3) + b3 ).
//   - R18: the 128-dim gather's "compulsory fill floor" (82MB: every XCD
//     touched the whole 12.8MB table) is broken by DIMENSION SLICING:
//     bufA stored slice-major [8][N][16dims=32B]; slice = blockIdx&7 so all
//     blocks of slice s land on XCD s (round-robin dispatch) and the 1.6MB
//     slice table is L2-RESIDENT. One wave = one node; lane = edge-slot(3b)
//     x dim-pair(3b): one instruction gathers 8 edges x 32B from L2.
//     ReLU applied per-slice; h1relu written bf16 [8][N][32B]; a tiny proj
//     kernel computes z = h1relu @ W23 (coalesced 12.8MB read).
//   - R14/R15: global atomics write through (~32B/op) -> LDS-atomic
//     two-level counting sort for CSR build.
//   - R17: z/z2 packed bf16 (20B/node), 10-dim aggs L2-resident.
//   - R11: don't fuse kernels with opposite resource profiles.
//   - GEMM1: bf16 MFMA 16x16x32, C via LDS round-trip.
// ---------------------------------------------------------------------------

typedef unsigned int uint;
typedef unsigned short u16;
typedef uint  uint4e  __attribute__((ext_vector_type(4)));
typedef float float4e __attribute__((ext_vector_type(4)));
typedef float float2e __attribute__((ext_vector_type(2)));
typedef uint  uint2e  __attribute__((ext_vector_type(2)));
typedef int   int2e   __attribute__((ext_vector_type(2)));
typedef int   int4e   __attribute__((ext_vector_type(4)));
using bf16x8 = __attribute__((ext_vector_type(8))) short;
using f32x4  = __attribute__((ext_vector_type(4))) float;

__device__ __forceinline__ float bf_lo(uint v) { return __uint_as_float(v << 16); }
__device__ __forceinline__ float bf_hi(uint v) { return __uint_as_float(v & 0xffff0000u); }
__device__ __forceinline__ u16 bf16_1(float a) {
    uint ua = __float_as_uint(a);
    ua = (ua + 0x7fffu + ((ua >> 16) & 1u)) >> 16;          // RNE
    return (u16)ua;
}
__device__ __forceinline__ uint pack_bf2(float a, float b) {
    return (uint)bf16_1(a) | ((uint)bf16_1(b) << 16);
}

// Blocks [0,nca): coarse histogram of dst buckets (dst>>8) in LDS.
// Block nca: Wt1 transpose + b23. Blocks nca+1..+5: W23 = W2@W3.
__global__ __launch_bounds__(256) void passA_wt(const int* __restrict__ ei, int E,
        int* __restrict__ cntA, int nbkt, int nca,
        const float* __restrict__ W1, const float* __restrict__ W2,
        const float* __restrict__ W3, const float* __restrict__ b2,
        u16* __restrict__ Wt1, float* __restrict__ W23, float* __restrict__ b23) {
    int tid = threadIdx.x, b = blockIdx.x;
    if (b < nca) {
        __shared__ int h[256];
        h[tid] = 0;
        __syncthreads();
        int ch = (E + nca - 1) / nca;
        int beg = b * ch, end = min(beg + ch, E);
        for (int e = beg + tid; e < end; e += 256)
            atomicAdd(&h[ei[E + e] >> 8], 1);               // LDS atomic
        __syncthreads();
        if (tid < nbkt) cntA[tid * nca + b] = h[tid];
    } else if (b == nca) {
        for (int i = 0; i < 64; ++i) {
            int idx = tid + i * 256;          // 16384 = 128*128
            int k = idx >> 7, c = idx & 127;
            Wt1[c * 128 + k] = bf16_1(W1[idx]);
        }
        int c = tid >> 4, j0 = tid & 15;
        float acc = 0.f;
        if (c < 10) {
#pragma unroll
            for (int j = 0; j < 128; j += 16)
                acc += b2[j + j0] * W3[(j + j0) * 10 + c];
        }
#pragma unroll
        for (int m = 1; m < 16; m <<= 1) acc += __shfl_xor(acc, m);
        if (c < 10 && j0 == 0) b23[c] = acc;
    } else {
        __shared__ float w3s[1280];
        for (int i = tid; i < 1280; i += 256) w3s[i] = W3[i];
        __syncthreads();
        int idx = (b - nca - 1) * 256 + tid;
        int k = idx / 10, c = idx % 10;
        const float* w2r = W2 + (size_t)k * 128;
        float a0 = 0.f, a1 = 0.f, a2 = 0.f, a3 = 0.f;
#pragma unroll
        for (int j = 0; j < 128; j += 4) {
            a0 += w2r[j + 0] * w3s[(j + 0) * 10 + c];
            a1 += w2r[j + 1] * w3s[(j + 1) * 10 + c];
            a2 += w2r[j + 2] * w3s[(j + 2) * 10 + c];
            a3 += w2r[j + 3] * w3s[(j + 3) * 10 + c];
        }
        W23[idx] = (a0 + a1) + (a2 + a3);
    }
}

// Per-bucket exclusive scan over the nca block counts; total -> btot[bucket].
__global__ __launch_bounds__(256) void scan1(int* __restrict__ cntA, int nca,
        int* __restrict__ btot) {
    __shared__ int s[256];
    int b = blockIdx.x, tid = threadIdx.x;
    int v = cntA[b * nca + tid];
    s[tid] = v;
    __syncthreads();
    for (int d = 1; d < 256; d <<= 1) {
        int t = (tid >= d) ? s[tid - d] : 0;
        __syncthreads();
        s[tid] += t;
        __syncthreads();
    }
    cntA[b * nca + tid] = s[tid] - v;
    if (tid == 255) btot[b] = s[255];
}

// Scatter edges into bucket-contiguous ebkt via LDS cursors.
__global__ __launch_bounds__(256) void passB(const int* __restrict__ ei, int E,
        const int* __restrict__ cntA, int nca, int nbkt,
        const int* __restrict__ btot, int2e* __restrict__ ebkt) {
    __shared__ int sc[256];
    __shared__ int cur[256];
    int tid = threadIdx.x, b = blockIdx.x;
    int v = (tid < nbkt) ? btot[tid] : 0;
    sc[tid] = v;
    __syncthreads();
    for (int d = 1; d < 256; d <<= 1) {
        int t = (tid >= d) ? sc[tid - d] : 0;
        __syncthreads();
        sc[tid] += t;
        __syncthreads();
    }
    cur[tid] = (sc[tid] - v) + ((tid < nbkt) ? cntA[tid * nca + b] : 0);
    __syncthreads();
    int ch = (E + nca - 1) / nca;
    int beg = b * ch, end = min(beg + ch, E);
    for (int e = beg + tid; e < end; e += 256) {
        int s = ei[e], d = ei[E + e];
        int pos = atomicAdd(&cur[d >> 8], 1);               // LDS atomic
        int2e pkt;
        pkt.x = s;
        pkt.y = d;
        ebkt[pos] = pkt;
    }
}

// Per-bucket fine counting sort: deg/dis/row_ptr + dst-sorted esort (src,dst).
__global__ __launch_bounds__(256) void passC(const int2e* __restrict__ ebkt,
        const int* __restrict__ btot, int2e* __restrict__ esort,
        int* __restrict__ row_ptr, float* __restrict__ dis, int n, int nbkt, int E) {
    __shared__ int sc[256];
    __shared__ int fc[256];
    __shared__ int s_base;
    int k = blockIdx.x, tid = threadIdx.x;
    int bt = (tid < nbkt) ? btot[tid] : 0;
    sc[tid] = bt;
    __syncthreads();
    for (int d = 1; d < 256; d <<= 1) {
        int t = (tid >= d) ? sc[tid - d] : 0;
        __syncthreads();
        sc[tid] += t;
        __syncthreads();
    }
    if (tid == k) s_base = sc[tid] - bt;
    fc[tid] = 0;
    __syncthreads();
    int base = s_base;
    int endb = base + btot[k];
    int node0 = k << 8;
    for (int i = base + tid; i < endb; i += 256)
        atomicAdd(&fc[ebkt[i].y & 255], 1);                 // LDS atomic
    __syncthreads();
    int v = fc[tid];
    sc[tid] = v;
    __syncthreads();
    for (int d = 1; d < 256; d <<= 1) {
        int t = (tid >= d) ? sc[tid - d] : 0;
        __syncthreads();
        sc[tid] += t;
        __syncthreads();
    }
    int excl = sc[tid] - v;
    if (node0 + tid < n) {
        dis[node0 + tid] = rsqrtf((float)(v + 1));          // +1 self-loop
        row_ptr[node0 + tid] = base + excl;
    }
    __syncthreads();
    fc[tid] = base + excl;
    __syncthreads();
    for (int i = base + tid; i < endb; i += 256) {
        int2e ed = ebkt[i];
        int pos = atomicAdd(&fc[ed.y & 255], 1);            // LDS atomic
        esort[pos] = ed;                                    // (src, dst)
    }
    if (k == 0 && tid == 0) row_ptr[n] = E;
}

// GEMM1: out = bf16(A @ W), written SLICE-MAJOR: out[s][node][8 uints],
// slice s = dims [16s, 16s+16). Wt bf16 [col][k]; C via LDS round-trip.
__global__ __launch_bounds__(256) void gemm_mfma(const float* __restrict__ A,
        const u16* __restrict__ Wt, uint* __restrict__ out, int n) {
    constexpr int LDA = 136;                 // 128 + 8 pad (bf16) -> 2-way LDS only
    __shared__ u16 as[64 * LDA];
    int tid = threadIdx.x;
    int wave = tid >> 6, lane = tid & 63;
    int row0 = blockIdx.x * 64;
    int l16 = lane & 15;
    int krow = (lane >> 4) * 8;

#pragma unroll
    for (int i = 0; i < 8; ++i) {
        int idx = tid + i * 256;
        int r = idx >> 5;
        int q = (idx & 31) * 4;
        float4e v = {0.f, 0.f, 0.f, 0.f};
        if (row0 + r < n)
            v = *reinterpret_cast<const float4e*>(A + (size_t)(row0 + r) * 128 + q);
        uint2e p;
        p.x = pack_bf2(v.x, v.y);
        p.y = pack_bf2(v.z, v.w);
        *reinterpret_cast<uint2e*>(&as[r * LDA + q]) = p;
    }

    bf16x8 b[2][4];
#pragma unroll
    for (int n2 = 0; n2 < 2; ++n2)
#pragma unroll
        for (int kb = 0; kb < 4; ++kb)
            b[n2][kb] = *reinterpret_cast<const bf16x8*>(
                Wt + (size_t)(wave * 32 + n2 * 16 + l16) * 128 + kb * 32 + krow);

    __syncthreads();

    f32x4 acc[4][2] = {};
#pragma unroll
    for (int m = 0; m < 4; ++m) {
#pragma unroll
        for (int kb = 0; kb < 4; ++kb) {
            bf16x8 a = *reinterpret_cast<const bf16x8*>(
                &as[(m * 16 + l16) * LDA + kb * 32 + krow]);
#pragma unroll
            for (int n2 = 0; n2 < 2; ++n2)
                acc[m][n2] = __builtin_amdgcn_mfma_f32_16x16x32_bf16(a, b[n2][kb], acc[m][n2], 0, 0, 0);
        }
    }

    __syncthreads();                         // as[] reuse as C-staging
    u16* cs = as;
#pragma unroll
    for (int m = 0; m < 4; ++m) {
        int rb = m * 16 + (lane >> 4) * 4;
#pragma unroll
        for (int n2 = 0; n2 < 2; ++n2) {
            int col = wave * 32 + n2 * 16 + l16;
#pragma unroll
            for (int r = 0; r < 4; ++r)
                cs[(rb + r) * 128 + col] = bf16_1(acc[m][n2][r]);
        }
    }
    __syncthreads();
#pragma unroll
    for (int i = 0; i < 4; ++i) {
        int idx = tid + i * 256;             // 1024 octs: row=idx>>4, oct o=idx&15
        int r = idx >> 4;
        int o = idx & 15;                    // dims [8o, 8o+8)
        int s = o >> 1;                      // slice
        int h = o & 1;                       // half within slice (4 uints)
        if (row0 + r < n)
            *reinterpret_cast<uint4e*>(out + (size_t)s * n * 8 + (size_t)(row0 + r) * 8 + h * 4) =
                *reinterpret_cast<const uint4e*>(&cs[r * 128 + o * 8]);
    }
}

// Sliced gather: slice = blockIdx&7 (-> same XCD under round-robin; 1.6MB
// slice table L2-resident). Wave = node; lane = edge-slot(lane>>3) x
// dim-pair(lane&7). hout[s][v][dp] = bf16 relu(agg + b1).
__global__ __launch_bounds__(256) void agg_slice_kernel(const uint* __restrict__ bufA,
        const int* __restrict__ row_ptr, const int2e* __restrict__ esort,
        const float* __restrict__ dis, const float* __restrict__ b1,
        uint* __restrict__ hout, int n) {
    int s = blockIdx.x & 7;
    int v = (int)((blockIdx.x >> 3) * 4 + (threadIdx.x >> 6));
    int lane = threadIdx.x & 63;
    if (v >= n) return;
    int eg = lane >> 3;                      // edge slot 0-7
    int dp = lane & 7;                       // dim pair 0-7
    const uint* tbl = bufA + (size_t)s * n * 8;
    float dv = dis[v];
    float ax = 0.f, ay = 0.f;
    int beg = row_ptr[v], end = row_ptr[v + 1];
    int e = beg;
    for (; e + 7 < end; e += 8) {
        int2e ed = esort[e + eg];
        uint t = tbl[(size_t)ed.x * 8 + dp];
        float w = dis[ed.x] * dv;
        ax += w * bf_lo(t);
        ay += w * bf_hi(t);
    }
    if (e < end) {                           // tail: rem in 1..7
        int rem = end - e;
        int2e ed = esort[e + (eg < rem ? eg : 0)];
        uint t = tbl[(size_t)ed.x * 8 + dp];
        float w = (eg < rem) ? dis[ed.x] * dv : 0.f;
        ax += w * bf_lo(t);
        ay += w * bf_hi(t);
    }
    // reduce over the 8 edge slots (lane bits 3..5)
    ax += __shfl_xor(ax, 8);  ay += __shfl_xor(ay, 8);
    ax += __shfl_xor(ax, 16); ay += __shfl_xor(ay, 16);
    ax += __shfl_xor(ax, 32); ay += __shfl_xor(ay, 32);
    // self-loop (once), bias, relu
    uint tv = tbl[(size_t)v * 8 + dp];
    float wv = dv * dv;
    ax += wv * bf_lo(tv);
    ay += wv * bf_hi(tv);
    int d0 = s * 16 + 2 * dp;
    ax = fmaxf(ax + b1[d0], 0.f);
    ay = fmaxf(ay + b1[d0 + 1], 0.f);
    if (eg == 0) hout[(size_t)s * n * 8 + (size_t)v * 8 + dp] = pack_bf2(ax, ay);
}

// Projection: z[v](packed bf16 x5) = h1relu[v] @ W23. Coalesced 32B reads
// per slice; W23 in LDS.
__global__ __launch_bounds__(256) void proj_kernel(const uint* __restrict__ hout,
        const float* __restrict__ W23, uint* __restrict__ z, int n) {
    __shared__ float w3s[1280];
    int tid = threadIdx.x;
    for (int i = tid; i < 1280; i += 256) w3s[i] = W23[i];
    __syncthreads();
    int v = blockIdx.x * 256 + tid;
    if (v >= n) return;
    float p[10] = {};
#pragma unroll
    for (int s = 0; s < 8; ++s) {
        uint4e c0 = *reinterpret_cast<const uint4e*>(hout + (size_t)s * n * 8 + (size_t)v * 8);
        uint4e c1 = *reinterpret_cast<const uint4e*>(hout + (size_t)s * n * 8 + (size_t)v * 8 + 4);
        uint u[8] = {c0.x, c0.y, c0.z, c0.w, c1.x, c1.y, c1.z, c1.w};
#pragma unroll
        for (int k = 0; k < 8; ++k) {
            int d = s * 16 + 2 * k;
            float lo = bf_lo(u[k]), hi = bf_hi(u[k]);
#pragma unroll
            for (int c = 0; c < 10; ++c)
                p[c] += lo * w3s[d * 10 + c] + hi * w3s[(d + 1) * 10 + c];
        }
    }
#pragma unroll
    for (int i = 0; i < 5; ++i)
        z[(size_t)v * 5 + i] = pack_bf2(p[2 * i], p[2 * i + 1]);
}

// Pass B/C: 10-dim aggregation over packed-bf16 z. 4 nodes/wave (16-lane
// groups); lanes 0-4 own dims (2gl,2gl+1). 8 edges in flight.
template <int FINAL>
__global__ __launch_bounds__(256) void agg10_kernel(const uint* __restrict__ zin,
        const int* __restrict__ row_ptr, const int2e* __restrict__ esort,
        const float* __restrict__ dis, const float* __restrict__ b23,
        const float* __restrict__ b3, void* __restrict__ zout, int n) {
    int wid = (int)((blockIdx.x * blockDim.x + threadIdx.x) >> 6);
    int lane = threadIdx.x & 63;
    int grp = lane >> 4, gl = lane & 15;
    int v = wid * 4 + grp;
    bool act = (v < n);
    bool dl = (gl < 5);
    int beg = act ? row_ptr[v] : 0;
    int end = act ? row_ptr[v + 1] : 0;
    float dv = act ? dis[v] : 0.f;
    float ax = 0.f, ay = 0.f, sw = 0.f;
    int e = beg;
    for (; e + 7 < end; e += 8) {
        int2e ed[8];
        uint zz[8];
        float wd[8];
#pragma unroll
        for (int j = 0; j < 8; ++j) ed[j] = esort[e + j];
#pragma unroll
        for (int j = 0; j < 8; ++j) {
            zz[j] = dl ? zin[(size_t)ed[j].x * 5 + gl] : 0u;
            wd[j] = dis[ed[j].x];
        }
#pragma unroll
        for (int j = 0; j < 8; ++j) {
            float w = wd[j] * dv;
            ax += w * bf_lo(zz[j]);
            ay += w * bf_hi(zz[j]);
            sw += w;
        }
    }
    for (; e < end; ++e) {
        int2e e0 = esort[e];
        uint z0 = dl ? zin[(size_t)e0.x * 5 + gl] : 0u;
        float w0 = dis[e0.x] * dv;
        ax += w0 * bf_lo(z0);
        ay += w0 * bf_hi(z0);
        sw += w0;
    }
    if (act) {
        float wv = dv * dv;
        uint zs = dl ? zin[(size_t)v * 5 + gl] : 0u;
        ax += wv * bf_lo(zs);
        ay += wv * bf_hi(zs);
        sw += wv;
    }
    if (FINAL == 0) {
        if (act && dl) ((uint*)zout)[(size_t)v * 5 + gl] = pack_bf2(ax, ay);
    } else {
        float pa = 0.f, pb = 0.f;
        if (dl) {
            pa = ax + sw * b23[2 * gl] + b3[2 * gl];
            pb = ay + sw * b23[2 * gl + 1] + b3[2 * gl + 1];
        }
        float m = dl ? fmaxf(pa, pb) : -3.4e38f;
#pragma unroll
        for (int mask = 1; mask < 16; mask <<= 1) m = fmaxf(m, __shfl_xor(m, mask));
        float s = dl ? (__expf(pa - m) + __expf(pb - m)) : 0.f;
#pragma unroll
        for (int mask = 1; mask < 16; mask <<= 1) s += __shfl_xor(s, mask);
        float ls = __logf(s);
        if (act && dl) {
            float2e o = {pa - m - ls, pb - m - ls};
            *reinterpret_cast<float2e*>((float*)zout + (size_t)v * 10 + 2 * gl) = o;
        }
    }
}

extern "C" void kernel_launch(void* const* d_in, const int* in_sizes, int n_in,
                              void* d_out, int out_size, void* d_ws, size_t ws_size,
                              hipStream_t stream) {
    const float* x  = (const float*)d_in[0];
    const int*   ei = (const int*)d_in[1];   // [2][E] int32
    const float* W1 = (const float*)d_in[2];
    const float* b1 = (const float*)d_in[3];
    const float* W2 = (const float*)d_in[4];
    const float* b2 = (const float*)d_in[5];
    const float* W3 = (const float*)d_in[6];
    const float* b3 = (const float*)d_in[7];
    int N = in_sizes[0] / 128;
    int E = in_sizes[1] / 2;
    int NBKT = (N + 255) >> 8;    // 196 for N=50000 (must be <= 256)
    const int NCA = 256;          // chunk blocks for passes A/B

    char* ws = (char*)d_ws;
    size_t off = 0;
    auto alloc = [&](size_t bytes) -> char* {
        char* p = ws + off;
        off = (off + bytes + 255) & ~(size_t)255;
        return p;
    };
    int*   cntA    = (int*)alloc((size_t)NBKT * NCA * 4);
    int*   btot    = (int*)alloc(256 * 4);
    int*   row_ptr = (int*)alloc(((size_t)N + 1) * 4);
    float* dis     = (float*)alloc((size_t)N * 4);
    u16*   Wt1     = (u16*)alloc(128 * 128 * 2);
    float* W23     = (float*)alloc(128 * 10 * 4);
    float* b23     = (float*)alloc(10 * 4);
    int2e* ebkt    = (int2e*)alloc((size_t)E * 8);         // bucket-sorted (src,dst)
    int2e* esort   = (int2e*)alloc((size_t)E * 8);         // dst-sorted (src,dst)
    uint*  bufA    = (uint*)alloc((size_t)N * 64 * 4);     // slice-major bf16 x@W1
    uint*  hbuf    = (uint*)alloc((size_t)N * 64 * 4);     // slice-major bf16 h1relu
    uint*  z       = (uint*)alloc((size_t)N * 5 * 4);      // packed bf16 h1@W23
    uint*  z2      = (uint*)alloc((size_t)N * 5 * 4);      // packed bf16 Agg(z)

    // --- preprocessing: LDS-atomic counting sort + weight prep ---
    passA_wt<<<NCA + 6, 256, 0, stream>>>(ei, E, cntA, NBKT, NCA, W1, W2, W3, b2,
                                          Wt1, W23, b23);
    gemm_mfma<<<(N + 63) / 64, 256, 0, stream>>>(x, Wt1, bufA, N);
    scan1<<<NBKT, 256, 0, stream>>>(cntA, NCA, btot);
    passB<<<NCA, 256, 0, stream>>>(ei, E, cntA, NCA, NBKT, btot, ebkt);
    passC<<<NBKT, 256, 0, stream>>>(ebkt, btot, esort, row_ptr, dis, N, NBKT, E);
    // --- sliced 128-dim gather (L2-resident slice tables) + projection ---
    agg_slice_kernel<<<8 * ((N + 3) / 4), 256, 0, stream>>>(bufA, row_ptr, esort, dis,
                                                            b1, hbuf, N);
    proj_kernel<<<(N + 255) / 256, 256, 0, stream>>>(hbuf, W23, z, N);
    // --- layers 2+3: two 10-dim aggregations (packed bf16, L2-resident) ---
    agg10_kernel<0><<<(N + 15) / 16, 256, 0, stream>>>(z, row_ptr, esort, dis, nullptr, nullptr, z2, N);
    agg10_kernel<1><<<(N + 15) / 16, 256, 0, stream>>>(z2, row_ptr, esort, dis, b23, b3, d_out, N);
}

// Round 19
// 127.994 us; speedup vs baseline: 1.6762x; 1.6762x over previous
//
#include <hip/hip_runtime.h>
#include <cstdint>
#include <cstddef>

// ---------------------------------------------------------------------------
// GCN: 3 layers, shared graph.
//   - Algebra: only layer 1 has ReLU; projection commutes with aggregation:
//       out = log_softmax( A^2 (relu(A xW1 + b1) W23) + s*(b2W3) + b3 ).
//     One 128-dim gather (compulsory L2-fill floor: ~83MB @ ~1.7TB/s = 49us,
//     invariant R7-R18), then 10-dim space (L2-resident).
//   - R18 lesson: dimension-slicing cut FETCH 83->33MB but became ISSUE-bound
//     (8x esort re-reads + 8x weight math): 49 -> 122us. Cutting fill only
//     pays if the replacement instruction stream is cheaper than the fill.
//     Full-row one-wave-per-node gather is optimal for this pattern.
//   - R14/R15: device-scope global atomics write through (~32B/op); the
//     LDS-atomic two-level counting sort removed ~46us of atomic tax.
//   - R17: z/z2 tables packed bf16 (20B/node); 10-dim aggs L2-resident.
//   - R11: don't fuse kernels with opposite resource profiles.
//   - GEMM1: bf16 MFMA 16x16x32, C via LDS round-trip (16B stores).
// ---------------------------------------------------------------------------

typedef unsigned int uint;
typedef unsigned short u16;
typedef uint  uint4e  __attribute__((ext_vector_type(4)));
typedef float float4e __attribute__((ext_vector_type(4)));
typedef float float2e __attribute__((ext_vector_type(2)));
typedef uint  uint2e  __attribute__((ext_vector_type(2)));
typedef int   int2e   __attribute__((ext_vector_type(2)));
typedef int   int4e   __attribute__((ext_vector_type(4)));
using bf16x8 = __attribute__((ext_vector_type(8))) short;
using f32x4  = __attribute__((ext_vector_type(4))) float;

__device__ __forceinline__ float bf_lo(uint v) { return __uint_as_float(v << 16); }
__device__ __forceinline__ float bf_hi(uint v) { return __uint_as_float(v & 0xffff0000u); }
__device__ __forceinline__ u16 bf16_1(float a) {
    uint ua = __float_as_uint(a);
    ua = (ua + 0x7fffu + ((ua >> 16) & 1u)) >> 16;          // RNE
    return (u16)ua;
}
__device__ __forceinline__ uint pack_bf2(float a, float b) {
    return (uint)bf16_1(a) | ((uint)bf16_1(b) << 16);
}

// Blocks [0,nca): coarse histogram of dst buckets (dst>>8) in LDS ->
// cntA[bucket*nca + block]. Block nca: Wt1 transpose + b23. Blocks nca+1..+5: W23.
__global__ __launch_bounds__(256) void passA_wt(const int* __restrict__ ei, int E,
        int* __restrict__ cntA, int nbkt, int nca,
        const float* __restrict__ W1, const float* __restrict__ W2,
        const float* __restrict__ W3, const float* __restrict__ b2,
        u16* __restrict__ Wt1, float* __restrict__ W23, float* __restrict__ b23) {
    int tid = threadIdx.x, b = blockIdx.x;
    if (b < nca) {
        __shared__ int h[256];
        h[tid] = 0;
        __syncthreads();
        int ch = (E + nca - 1) / nca;
        int beg = b * ch, end = min(beg + ch, E);
        for (int e = beg + tid; e < end; e += 256)
            atomicAdd(&h[ei[E + e] >> 8], 1);               // LDS atomic
        __syncthreads();
        if (tid < nbkt) cntA[tid * nca + b] = h[tid];       // all entries written
    } else if (b == nca) {
        for (int i = 0; i < 64; ++i) {
            int idx = tid + i * 256;          // 16384 = 128*128
            int k = idx >> 7, c = idx & 127;
            Wt1[c * 128 + k] = bf16_1(W1[idx]);
        }
        // b23[c] = sum_j b2[j]*W3[j][c]: 16 lanes per output.
        int c = tid >> 4, j0 = tid & 15;
        float acc = 0.f;
        if (c < 10) {
#pragma unroll
            for (int j = 0; j < 128; j += 16)
                acc += b2[j + j0] * W3[(j + j0) * 10 + c];
        }
#pragma unroll
        for (int m = 1; m < 16; m <<= 1) acc += __shfl_xor(acc, m);
        if (c < 10 && j0 == 0) b23[c] = acc;
    } else {
        // W23: one output per thread, idx = (b-nca-1)*256 + tid (5*256=1280).
        __shared__ float w3s[1280];
        for (int i = tid; i < 1280; i += 256) w3s[i] = W3[i];
        __syncthreads();
        int idx = (b - nca - 1) * 256 + tid;
        int k = idx / 10, c = idx % 10;
        const float* w2r = W2 + (size_t)k * 128;
        float a0 = 0.f, a1 = 0.f, a2 = 0.f, a3 = 0.f;
#pragma unroll
        for (int j = 0; j < 128; j += 4) {
            a0 += w2r[j + 0] * w3s[(j + 0) * 10 + c];
            a1 += w2r[j + 1] * w3s[(j + 1) * 10 + c];
            a2 += w2r[j + 2] * w3s[(j + 2) * 10 + c];
            a3 += w2r[j + 3] * w3s[(j + 3) * 10 + c];
        }
        W23[idx] = (a0 + a1) + (a2 + a3);
    }
}

// Per-bucket exclusive scan over the nca block counts; total -> btot[bucket].
__global__ __launch_bounds__(256) void scan1(int* __restrict__ cntA, int nca,
        int* __restrict__ btot) {
    __shared__ int s[256];
    int b = blockIdx.x, tid = threadIdx.x;   // b = bucket; tid = chunk-block
    int v = cntA[b * nca + tid];
    s[tid] = v;
    __syncthreads();
    for (int d = 1; d < 256; d <<= 1) {
        int t = (tid >= d) ? s[tid - d] : 0;
        __syncthreads();
        s[tid] += t;
        __syncthreads();
    }
    cntA[b * nca + tid] = s[tid] - v;        // exclusive within bucket
    if (tid == 255) btot[b] = s[255];
}

// Scatter edges into bucket-contiguous ebkt via LDS cursors.
// Bucket bases derived by redundant LDS scan of btot. Edge reads via int4.
__global__ __launch_bounds__(256) void passB(const int* __restrict__ ei, int E,
        const int* __restrict__ cntA, int nca, int nbkt,
        const int* __restrict__ btot, int2e* __restrict__ ebkt) {
    __shared__ int sc[256];
    __shared__ int cur[256];
    int tid = threadIdx.x, b = blockIdx.x;
    int v = (tid < nbkt) ? btot[tid] : 0;
    sc[tid] = v;
    __syncthreads();
    for (int d = 1; d < 256; d <<= 1) {
        int t = (tid >= d) ? sc[tid - d] : 0;
        __syncthreads();
        sc[tid] += t;
        __syncthreads();
    }
    cur[tid] = (sc[tid] - v) + ((tid < nbkt) ? cntA[tid * nca + b] : 0);
    __syncthreads();
    int ch = (E + nca - 1) / nca;            // NOTE: must match passA chunking
    int beg = b * ch, end = min(beg + ch, E);
    int e = beg + tid * 4;
    // vectorized main: each thread handles 4 consecutive edges
    for (; e + 3 < end; e += 1024) {
        int4e s4 = *reinterpret_cast<const int4e*>(ei + e);
        int4e d4 = *reinterpret_cast<const int4e*>(ei + E + e);
#pragma unroll
        for (int k = 0; k < 4; ++k) {
            int s = k == 0 ? s4.x : k == 1 ? s4.y : k == 2 ? s4.z : s4.w;
            int d = k == 0 ? d4.x : k == 1 ? d4.y : k == 2 ? d4.z : d4.w;
            int pos = atomicAdd(&cur[d >> 8], 1);           // LDS atomic
            int2e pkt;
            pkt.x = s;
            pkt.y = d;
            ebkt[pos] = pkt;
        }
    }
    for (; e < end; ++e) {                   // tail (unaligned remainder)
        int s = ei[e], d = ei[E + e];
        int pos = atomicAdd(&cur[d >> 8], 1);
        int2e pkt;
        pkt.x = s;
        pkt.y = d;
        ebkt[pos] = pkt;
    }
}

// Per-bucket fine counting sort: deg/dis/row_ptr + dst-sorted esort (src,dst).
// Bucket base via redundant LDS scan of btot.
__global__ __launch_bounds__(256) void passC(const int2e* __restrict__ ebkt,
        const int* __restrict__ btot, int2e* __restrict__ esort,
        int* __restrict__ row_ptr, float* __restrict__ dis, int n, int nbkt, int E) {
    __shared__ int sc[256];
    __shared__ int fc[256];
    __shared__ int s_base;
    int k = blockIdx.x, tid = threadIdx.x;
    int bt = (tid < nbkt) ? btot[tid] : 0;
    sc[tid] = bt;
    __syncthreads();
    for (int d = 1; d < 256; d <<= 1) {
        int t = (tid >= d) ? sc[tid - d] : 0;
        __syncthreads();
        sc[tid] += t;
        __syncthreads();
    }
    if (tid == k) s_base = sc[tid] - bt;                    // excl base of bucket k
    fc[tid] = 0;
    __syncthreads();
    int base = s_base;
    int endb = base + btot[k];
    int node0 = k << 8;
    for (int i = base + tid; i < endb; i += 256)
        atomicAdd(&fc[ebkt[i].y & 255], 1);                 // LDS atomic
    __syncthreads();
    int v = fc[tid];
    sc[tid] = v;
    __syncthreads();
    for (int d = 1; d < 256; d <<= 1) {
        int t = (tid >= d) ? sc[tid - d] : 0;
        __syncthreads();
        sc[tid] += t;
        __syncthreads();
    }
    int excl = sc[tid] - v;
    if (node0 + tid < n) {
        dis[node0 + tid] = rsqrtf((float)(v + 1));          // +1 self-loop
        row_ptr[node0 + tid] = base + excl;
    }
    __syncthreads();
    fc[tid] = base + excl;                                  // reuse as cursor
    __syncthreads();
    for (int i = base + tid; i < endb; i += 256) {
        int2e ed = ebkt[i];
        int pos = atomicAdd(&fc[ed.y & 255], 1);            // LDS atomic
        esort[pos] = ed;                                    // (src, dst)
    }
    if (k == 0 && tid == 0) row_ptr[n] = E;
}

// out u16[n][128] = bf16( A[n][128] @ W ),  W given as Wt bf16 [col][k].
__global__ __launch_bounds__(256) void gemm_mfma(const float* __restrict__ A,
        const u16* __restrict__ Wt, u16* __restrict__ out, int n) {
    constexpr int LDA = 136;                 // 128 + 8 pad (bf16) -> 2-way LDS only
    __shared__ u16 as[64 * LDA];
    int tid = threadIdx.x;
    int wave = tid >> 6, lane = tid & 63;
    int row0 = blockIdx.x * 64;
    int l16 = lane & 15;
    int krow = (lane >> 4) * 8;              // k-octet within 32-wide K block

#pragma unroll
    for (int i = 0; i < 8; ++i) {
        int idx = tid + i * 256;             // 2048 quads of 4 f32
        int r = idx >> 5;
        int q = (idx & 31) * 4;
        float4e v = {0.f, 0.f, 0.f, 0.f};
        if (row0 + r < n)
            v = *reinterpret_cast<const float4e*>(A + (size_t)(row0 + r) * 128 + q);
        uint2e p;
        p.x = pack_bf2(v.x, v.y);
        p.y = pack_bf2(v.z, v.w);
        *reinterpret_cast<uint2e*>(&as[r * LDA + q]) = p;
    }

    bf16x8 b[2][4];
#pragma unroll
    for (int n2 = 0; n2 < 2; ++n2)
#pragma unroll
        for (int kb = 0; kb < 4; ++kb)
            b[n2][kb] = *reinterpret_cast<const bf16x8*>(
                Wt + (size_t)(wave * 32 + n2 * 16 + l16) * 128 + kb * 32 + krow);

    __syncthreads();

    f32x4 acc[4][2] = {};
#pragma unroll
    for (int m = 0; m < 4; ++m) {
#pragma unroll
        for (int kb = 0; kb < 4; ++kb) {
            bf16x8 a = *reinterpret_cast<const bf16x8*>(
                &as[(m * 16 + l16) * LDA + kb * 32 + krow]);
#pragma unroll
            for (int n2 = 0; n2 < 2; ++n2)
                acc[m][n2] = __builtin_amdgcn_mfma_f32_16x16x32_bf16(a, b[n2][kb], acc[m][n2], 0, 0, 0);
        }
    }

    __syncthreads();                         // as[] reuse as C-staging
    u16* cs = as;
#pragma unroll
    for (int m = 0; m < 4; ++m) {
        int rb = m * 16 + (lane >> 4) * 4;
#pragma unroll
        for (int n2 = 0; n2 < 2; ++n2) {
            int col = wave * 32 + n2 * 16 + l16;
#pragma unroll
            for (int r = 0; r < 4; ++r)
                cs[(rb + r) * 128 + col] = bf16_1(acc[m][n2][r]);
        }
    }
    __syncthreads();
#pragma unroll
    for (int i = 0; i < 4; ++i) {
        int idx = tid + i * 256;             // 1024 octs: row=idx>>4, oct=(idx&15)
        int r = idx >> 4;
        int q = (idx & 15) * 8;
        if (row0 + r < n)
            *reinterpret_cast<uint4e*>(out + (size_t)(row0 + r) * 128 + q) =
                *reinterpret_cast<const uint4e*>(&cs[r * 128 + q]);
    }
}

// Full-wave gather with on-the-fly norm: esort = (src,dst); w = dis[s]*dis[v].
// Lane owns dims 2*lane..2*lane+1, 8 edges in flight.
__device__ __forceinline__ void gather_accum(const uint* __restrict__ xw,
        const int2e* __restrict__ esort, const float* __restrict__ dis,
        int v, int lane, int beg, int end, float& ax, float& ay) {
    float dv = dis[v];
    int e = beg;
    for (; e + 7 < end; e += 8) {
        int2e ed[8];
        uint vv[8];
        float wd[8];
#pragma unroll
        for (int j = 0; j < 8; ++j) ed[j] = esort[e + j];
#pragma unroll
        for (int j = 0; j < 8; ++j) {
            vv[j] = xw[(size_t)ed[j].x * 64 + lane];
            wd[j] = dis[ed[j].x];
        }
#pragma unroll
        for (int j = 0; j < 8; ++j) {
            float w = wd[j] * dv;
            ax += w * bf_lo(vv[j]);
            ay += w * bf_hi(vv[j]);
        }
    }
    for (; e + 1 < end; e += 2) {
        int2e e0 = esort[e];
        int2e e1 = esort[e + 1];
        uint v0 = xw[(size_t)e0.x * 64 + lane];
        uint v1 = xw[(size_t)e1.x * 64 + lane];
        float w0 = dis[e0.x] * dv, w1 = dis[e1.x] * dv;
        ax += w0 * bf_lo(v0); ay += w0 * bf_hi(v0);
        ax += w1 * bf_lo(v1); ay += w1 * bf_hi(v1);
    }
    if (e < end) {
        int2e e0 = esort[e];
        uint v0 = xw[(size_t)e0.x * 64 + lane];
        float w0 = dis[e0.x] * dv;
        ax += w0 * bf_lo(v0); ay += w0 * bf_hi(v0);
    }
    float wv = dv * dv;                            // self-loop norm
    uint vs = xw[(size_t)v * 64 + lane];
    ax += wv * bf_lo(vs); ay += wv * bf_hi(vs);
}

// Pass A: z[v] = packed bf16 of relu(Agg(x@W1)[v] + b1) @ W23  (5 x u32/node).
__global__ __launch_bounds__(256) void agg_proj_kernel(const uint* __restrict__ xw,
        const int* __restrict__ row_ptr, const int2e* __restrict__ esort,
        const float* __restrict__ dis, const float* __restrict__ b1,
        const float* __restrict__ W23, uint* __restrict__ z, int n) {
    int v = (int)((blockIdx.x * blockDim.x + threadIdx.x) >> 6);
    int lane = threadIdx.x & 63;
    if (v >= n) return;
    float ax = 0.f, ay = 0.f;
    gather_accum(xw, esort, dis, v, lane, row_ptr[v], row_ptr[v + 1], ax, ay);
    ax = fmaxf(ax + b1[lane * 2], 0.f);
    ay = fmaxf(ay + b1[lane * 2 + 1], 0.f);
    const float* w0 = W23 + (size_t)lane * 20;     // this lane's 2 rows of W23
    float p[10];
#pragma unroll
    for (int c = 0; c < 10; ++c) p[c] = ax * w0[c] + ay * w0[10 + c];
#pragma unroll
    for (int c = 0; c < 10; ++c) {
#pragma unroll
        for (int d = 1; d < 64; d <<= 1) p[c] += __shfl_xor(p[c], d);
    }
    if (lane < 5) z[(size_t)v * 5 + lane] = pack_bf2(p[2 * lane], p[2 * lane + 1]);
}

// Pass B/C: 10-dim aggregation over packed-bf16 z. 4 nodes per wave (16-lane
// groups); lanes 0-4 of each group own dims (2gl, 2gl+1). 8 edges in flight.
// FINAL=0: zout(packed) = Agg(zin).
// FINAL=1: out(f32) = log_softmax(Agg(zin) + s*b23 + b3).
template <int FINAL>
__global__ __launch_bounds__(256) void agg10_kernel(const uint* __restrict__ zin,
        const int* __restrict__ row_ptr, const int2e* __restrict__ esort,
        const float* __restrict__ dis, const float* __restrict__ b23,
        const float* __restrict__ b3, void* __restrict__ zout, int n) {
    int wid = (int)((blockIdx.x * blockDim.x + threadIdx.x) >> 6);
    int lane = threadIdx.x & 63;
    int grp = lane >> 4, gl = lane & 15;
    int v = wid * 4 + grp;
    bool act = (v < n);
    bool dl = (gl < 5);
    int beg = act ? row_ptr[v] : 0;
    int end = act ? row_ptr[v + 1] : 0;
    float dv = act ? dis[v] : 0.f;
    float ax = 0.f, ay = 0.f, sw = 0.f;
    int e = beg;
    for (; e + 7 < end; e += 8) {
        int2e ed[8];
        uint zz[8];
        float wd[8];
#pragma unroll
        for (int j = 0; j < 8; ++j) ed[j] = esort[e + j];
#pragma unroll
        for (int j = 0; j < 8; ++j) {
            zz[j] = dl ? zin[(size_t)ed[j].x * 5 + gl] : 0u;
            wd[j] = dis[ed[j].x];
        }
#pragma unroll
        for (int j = 0; j < 8; ++j) {
            float w = wd[j] * dv;
            ax += w * bf_lo(zz[j]);
            ay += w * bf_hi(zz[j]);
            sw += w;
        }
    }
    for (; e < end; ++e) {
        int2e e0 = esort[e];
        uint z0 = dl ? zin[(size_t)e0.x * 5 + gl] : 0u;
        float w0 = dis[e0.x] * dv;
        ax += w0 * bf_lo(z0);
        ay += w0 * bf_hi(z0);
        sw += w0;
    }
    if (act) {
        float wv = dv * dv;                        // self-loop
        uint zs = dl ? zin[(size_t)v * 5 + gl] : 0u;
        ax += wv * bf_lo(zs);
        ay += wv * bf_hi(zs);
        sw += wv;
    }
    if (FINAL == 0) {
        if (act && dl) ((uint*)zout)[(size_t)v * 5 + gl] = pack_bf2(ax, ay);
    } else {
        float pa = 0.f, pb = 0.f;
        if (dl) {
            pa = ax + sw * b23[2 * gl] + b3[2 * gl];
            pb = ay + sw * b23[2 * gl + 1] + b3[2 * gl + 1];
        }
        float m = dl ? fmaxf(pa, pb) : -3.4e38f;
#pragma unroll
        for (int mask = 1; mask < 16; mask <<= 1) m = fmaxf(m, __shfl_xor(m, mask));
        float s = dl ? (__expf(pa - m) + __expf(pb - m)) : 0.f;
#pragma unroll
        for (int mask = 1; mask < 16; mask <<= 1) s += __shfl_xor(s, mask);
        float ls = __logf(s);
        if (act && dl) {
            float2e o = {pa - m - ls, pb - m - ls};
            *reinterpret_cast<float2e*>((float*)zout + (size_t)v * 10 + 2 * gl) = o;
        }
    }
}

extern "C" void kernel_launch(void* const* d_in, const int* in_sizes, int n_in,
                              void* d_out, int out_size, void* d_ws, size_t ws_size,
                              hipStream_t stream) {
    const float* x  = (const float*)d_in[0];
    const int*   ei = (const int*)d_in[1];   // [2][E] int32
    const float* W1 = (const float*)d_in[2];
    const float* b1 = (const float*)d_in[3];
    const float* W2 = (const float*)d_in[4];
    const float* b2 = (const float*)d_in[5];
    const float* W3 = (const float*)d_in[6];
    const float* b3 = (const float*)d_in[7];
    int N = in_sizes[0] / 128;
    int E = in_sizes[1] / 2;
    int NBKT = (N + 255) >> 8;    // 196 for N=50000 (must be <= 256)
    const int NCA = 256;          // chunk blocks for passes A/B

    char* ws = (char*)d_ws;
    size_t off = 0;
    auto alloc = [&](size_t bytes) -> char* {
        char* p = ws + off;
        off = (off + bytes + 255) & ~(size_t)255;
        return p;
    };
    int*   cntA    = (int*)alloc((size_t)NBKT * NCA * 4);  // (bucket x block) counts
    int*   btot    = (int*)alloc(256 * 4);
    int*   row_ptr = (int*)alloc(((size_t)N + 1) * 4);
    float* dis     = (float*)alloc((size_t)N * 4);
    u16*   Wt1     = (u16*)alloc(128 * 128 * 2);
    float* W23     = (float*)alloc(128 * 10 * 4);
    float* b23     = (float*)alloc(10 * 4);
    int2e* ebkt    = (int2e*)alloc((size_t)E * 8);         // bucket-sorted (src,dst)
    int2e* esort   = (int2e*)alloc((size_t)E * 8);         // dst-sorted (src,dst)
    uint*  bufA    = (uint*)alloc((size_t)N * 64 * 4);     // bf16x2 packed x@W1
    uint*  z       = (uint*)alloc((size_t)N * 5 * 4);      // packed bf16 h1@W23 (1MB)
    uint*  z2      = (uint*)alloc((size_t)N * 5 * 4);      // packed bf16 Agg(z)

    // --- preprocessing: LDS-atomic counting sort + weight prep (no memset) ---
    passA_wt<<<NCA + 6, 256, 0, stream>>>(ei, E, cntA, NBKT, NCA, W1, W2, W3, b2,
                                          Wt1, W23, b23);
    // layer-1 GEMM (needs Wt1 from passA_wt)
    gemm_mfma<<<(N + 63) / 64, 256, 0, stream>>>(x, Wt1, (u16*)bufA, N);
    scan1<<<NBKT, 256, 0, stream>>>(cntA, NCA, btot);
    passB<<<NCA, 256, 0, stream>>>(ei, E, cntA, NCA, NBKT, btot, ebkt);
    passC<<<NBKT, 256, 0, stream>>>(ebkt, btot, esort, row_ptr, dis, N, NBKT, E);
    // --- the single 128-dim gather, fused with ReLU+projection ---
    agg_proj_kernel<<<(N + 3) / 4, 256, 0, stream>>>(bufA, row_ptr, esort, dis, b1, W23, z, N);
    // --- layers 2+3: two 10-dim aggregations (packed bf16, L2-resident) ---
    agg10_kernel<0><<<(N + 15) / 16, 256, 0, stream>>>(z, row_ptr, esort, dis, nullptr, nullptr, z2, N);
    agg10_kernel<1><<<(N + 15) / 16, 256, 0, stream>>>(z2, row_ptr, esort, dis, b23, b3, d_out, N);
}

// Round 20
// 123.537 us; speedup vs baseline: 1.7367x; 1.0361x over previous
//
#include <hip/hip_runtime.h>
#include <cstdint>
#include <cstddef>

// ---------------------------------------------------------------------------
// GCN: 3 layers, shared graph.
//   - Algebra: only layer 1 has ReLU; projection commutes with aggregation:
//       out = log_softmax( A^2 (relu(A xW1 + b1) W23) + s*(b2W3) + b3 ).
//     One 128-dim gather (compulsory L2-fill floor: ~83MB @ ~1.7TB/s = 49us,
//     invariant R7-R19), then 10-dim space (L2-resident).
//   - R20: node ids < 2^16 -> ebkt packs (dst<<16|src) in u32 (halves passB
//     write + passC read); esort stores ONLY src as u16 (dst == v is wave-
//     uniform in the gathers) -> edge stream per gather pass 6.4->1.6MB.
//   - R18 lesson: dimension-slicing cut FETCH but became issue-bound (8x
//     esort re-reads): cutting fill only pays if the replacement instruction
//     stream is cheaper. Full-row one-wave-per-node gather is optimal here.
//   - R14/R15: device-scope global atomics write through (~32B/op); the
//     LDS-atomic two-level counting sort removed ~46us of atomic tax.
//   - R17: z/z2 tables packed bf16 (20B/node); 10-dim aggs L2-resident.
//   - R11: don't fuse kernels with opposite resource profiles.
//   - GEMM1: bf16 MFMA 16x16x32, C via LDS round-trip (16B stores).
// ---------------------------------------------------------------------------

typedef unsigned int uint;
typedef unsigned short u16;
typedef uint  uint4e  __attribute__((ext_vector_type(4)));
typedef float float4e __attribute__((ext_vector_type(4)));
typedef float float2e __attribute__((ext_vector_type(2)));
typedef uint  uint2e  __attribute__((ext_vector_type(2)));
typedef int   int4e   __attribute__((ext_vector_type(4)));
using bf16x8 = __attribute__((ext_vector_type(8))) short;
using f32x4  = __attribute__((ext_vector_type(4))) float;

__device__ __forceinline__ float bf_lo(uint v) { return __uint_as_float(v << 16); }
__device__ __forceinline__ float bf_hi(uint v) { return __uint_as_float(v & 0xffff0000u); }
__device__ __forceinline__ u16 bf16_1(float a) {
    uint ua = __float_as_uint(a);
    ua = (ua + 0x7fffu + ((ua >> 16) & 1u)) >> 16;          // RNE
    return (u16)ua;
}
__device__ __forceinline__ uint pack_bf2(float a, float b) {
    return (uint)bf16_1(a) | ((uint)bf16_1(b) << 16);
}

// Blocks [0,nca): coarse histogram of dst buckets (dst>>8) in LDS ->
// cntA[bucket*nca + block]. Block nca: Wt1 transpose + b23. Blocks nca+1..+5: W23.
__global__ __launch_bounds__(256) void passA_wt(const int* __restrict__ ei, int E,
        int* __restrict__ cntA, int nbkt, int nca,
        const float* __restrict__ W1, const float* __restrict__ W2,
        const float* __restrict__ W3, const float* __restrict__ b2,
        u16* __restrict__ Wt1, float* __restrict__ W23, float* __restrict__ b23) {
    int tid = threadIdx.x, b = blockIdx.x;
    if (b < nca) {
        __shared__ int h[256];
        h[tid] = 0;
        __syncthreads();
        int ch = (E + nca - 1) / nca;
        int beg = b * ch, end = min(beg + ch, E);
        for (int e = beg + tid; e < end; e += 256)
            atomicAdd(&h[ei[E + e] >> 8], 1);               // LDS atomic
        __syncthreads();
        if (tid < nbkt) cntA[tid * nca + b] = h[tid];       // all entries written
    } else if (b == nca) {
        for (int i = 0; i < 64; ++i) {
            int idx = tid + i * 256;          // 16384 = 128*128
            int k = idx >> 7, c = idx & 127;
            Wt1[c * 128 + k] = bf16_1(W1[idx]);
        }
        // b23[c] = sum_j b2[j]*W3[j][c]: 16 lanes per output.
        int c = tid >> 4, j0 = tid & 15;
        float acc = 0.f;
        if (c < 10) {
#pragma unroll
            for (int j = 0; j < 128; j += 16)
                acc += b2[j + j0] * W3[(j + j0) * 10 + c];
        }
#pragma unroll
        for (int m = 1; m < 16; m <<= 1) acc += __shfl_xor(acc, m);
        if (c < 10 && j0 == 0) b23[c] = acc;
    } else {
        // W23: one output per thread, idx = (b-nca-1)*256 + tid (5*256=1280).
        __shared__ float w3s[1280];
        for (int i = tid; i < 1280; i += 256) w3s[i] = W3[i];
        __syncthreads();
        int idx = (b - nca - 1) * 256 + tid;
        int k = idx / 10, c = idx % 10;
        const float* w2r = W2 + (size_t)k * 128;
        float a0 = 0.f, a1 = 0.f, a2 = 0.f, a3 = 0.f;
#pragma unroll
        for (int j = 0; j < 128; j += 4) {
            a0 += w2r[j + 0] * w3s[(j + 0) * 10 + c];
            a1 += w2r[j + 1] * w3s[(j + 1) * 10 + c];
            a2 += w2r[j + 2] * w3s[(j + 2) * 10 + c];
            a3 += w2r[j + 3] * w3s[(j + 3) * 10 + c];
        }
        W23[idx] = (a0 + a1) + (a2 + a3);
    }
}

// Per-bucket exclusive scan over the nca block counts; total -> btot[bucket].
__global__ __launch_bounds__(256) void scan1(int* __restrict__ cntA, int nca,
        int* __restrict__ btot) {
    __shared__ int s[256];
    int b = blockIdx.x, tid = threadIdx.x;   // b = bucket; tid = chunk-block
    int v = cntA[b * nca + tid];
    s[tid] = v;
    __syncthreads();
    for (int d = 1; d < 256; d <<= 1) {
        int t = (tid >= d) ? s[tid - d] : 0;
        __syncthreads();
        s[tid] += t;
        __syncthreads();
    }
    cntA[b * nca + tid] = s[tid] - v;        // exclusive within bucket
    if (tid == 255) btot[b] = s[255];
}

// Scatter edges into bucket-contiguous ebkt (u32: dst<<16|src) via LDS cursors.
__global__ __launch_bounds__(256) void passB(const int* __restrict__ ei, int E,
        const int* __restrict__ cntA, int nca, int nbkt,
        const int* __restrict__ btot, uint* __restrict__ ebkt) {
    __shared__ int sc[256];
    __shared__ int cur[256];
    int tid = threadIdx.x, b = blockIdx.x;
    int v = (tid < nbkt) ? btot[tid] : 0;
    sc[tid] = v;
    __syncthreads();
    for (int d = 1; d < 256; d <<= 1) {
        int t = (tid >= d) ? sc[tid - d] : 0;
        __syncthreads();
        sc[tid] += t;
        __syncthreads();
    }
    cur[tid] = (sc[tid] - v) + ((tid < nbkt) ? cntA[tid * nca + b] : 0);
    __syncthreads();
    int ch = (E + nca - 1) / nca;            // must match passA chunking
    int beg = b * ch, end = min(beg + ch, E);
    int e = beg + tid * 4;
    for (; e + 3 < end; e += 1024) {
        int4e s4 = *reinterpret_cast<const int4e*>(ei + e);
        int4e d4 = *reinterpret_cast<const int4e*>(ei + E + e);
#pragma unroll
        for (int k = 0; k < 4; ++k) {
            int s = k == 0 ? s4.x : k == 1 ? s4.y : k == 2 ? s4.z : s4.w;
            int d = k == 0 ? d4.x : k == 1 ? d4.y : k == 2 ? d4.z : d4.w;
            int pos = atomicAdd(&cur[d >> 8], 1);           // LDS atomic
            ebkt[pos] = ((uint)d << 16) | (uint)s;
        }
    }
    for (; e < end; ++e) {
        int s = ei[e], d = ei[E + e];
        int pos = atomicAdd(&cur[d >> 8], 1);
        ebkt[pos] = ((uint)d << 16) | (uint)s;
    }
}

// Per-bucket fine counting sort: deg/dis/row_ptr + dst-sorted esort (u16 src).
__global__ __launch_bounds__(256) void passC(const uint* __restrict__ ebkt,
        const int* __restrict__ btot, u16* __restrict__ esort,
        int* __restrict__ row_ptr, float* __restrict__ dis, int n, int nbkt, int E) {
    __shared__ int sc[256];
    __shared__ int fc[256];
    __shared__ int s_base;
    int k = blockIdx.x, tid = threadIdx.x;
    int bt = (tid < nbkt) ? btot[tid] : 0;
    sc[tid] = bt;
    __syncthreads();
    for (int d = 1; d < 256; d <<= 1) {
        int t = (tid >= d) ? sc[tid - d] : 0;
        __syncthreads();
        sc[tid] += t;
        __syncthreads();
    }
    if (tid == k) s_base = sc[tid] - bt;                    // excl base of bucket k
    fc[tid] = 0;
    __syncthreads();
    int base = s_base;
    int endb = base + btot[k];
    int node0 = k << 8;
    for (int i = base + tid; i < endb; i += 256)
        atomicAdd(&fc[(ebkt[i] >> 16) & 255], 1);           // LDS atomic
    __syncthreads();
    int v = fc[tid];
    sc[tid] = v;
    __syncthreads();
    for (int d = 1; d < 256; d <<= 1) {
        int t = (tid >= d) ? sc[tid - d] : 0;
        __syncthreads();
        sc[tid] += t;
        __syncthreads();
    }
    int excl = sc[tid] - v;
    if (node0 + tid < n) {
        dis[node0 + tid] = rsqrtf((float)(v + 1));          // +1 self-loop
        row_ptr[node0 + tid] = base + excl;
    }
    __syncthreads();
    fc[tid] = base + excl;                                  // reuse as cursor
    __syncthreads();
    for (int i = base + tid; i < endb; i += 256) {
        uint ed = ebkt[i];
        int pos = atomicAdd(&fc[(ed >> 16) & 255], 1);      // LDS atomic
        esort[pos] = (u16)(ed & 0xffffu);                   // src only
    }
    if (k == 0 && tid == 0) row_ptr[n] = E;
}

// out u16[n][128] = bf16( A[n][128] @ W ),  W given as Wt bf16 [col][k].
__global__ __launch_bounds__(256) void gemm_mfma(const float* __restrict__ A,
        const u16* __restrict__ Wt, u16* __restrict__ out, int n) {
    constexpr int LDA = 136;                 // 128 + 8 pad (bf16) -> 2-way LDS only
    __shared__ u16 as[64 * LDA];
    int tid = threadIdx.x;
    int wave = tid >> 6, lane = tid & 63;
    int row0 = blockIdx.x * 64;
    int l16 = lane & 15;
    int krow = (lane >> 4) * 8;              // k-octet within 32-wide K block

#pragma unroll
    for (int i = 0; i < 8; ++i) {
        int idx = tid + i * 256;             // 2048 quads of 4 f32
        int r = idx >> 5;
        int q = (idx & 31) * 4;
        float4e v = {0.f, 0.f, 0.f, 0.f};
        if (row0 + r < n)
            v = *reinterpret_cast<const float4e*>(A + (size_t)(row0 + r) * 128 + q);
        uint2e p;
        p.x = pack_bf2(v.x, v.y);
        p.y = pack_bf2(v.z, v.w);
        *reinterpret_cast<uint2e*>(&as[r * LDA + q]) = p;
    }

    bf16x8 b[2][4];
#pragma unroll
    for (int n2 = 0; n2 < 2; ++n2)
#pragma unroll
        for (int kb = 0; kb < 4; ++kb)
            b[n2][kb] = *reinterpret_cast<const bf16x8*>(
                Wt + (size_t)(wave * 32 + n2 * 16 + l16) * 128 + kb * 32 + krow);

    __syncthreads();

    f32x4 acc[4][2] = {};
#pragma unroll
    for (int m = 0; m < 4; ++m) {
#pragma unroll
        for (int kb = 0; kb < 4; ++kb) {
            bf16x8 a = *reinterpret_cast<const bf16x8*>(
                &as[(m * 16 + l16) * LDA + kb * 32 + krow]);
#pragma unroll
            for (int n2 = 0; n2 < 2; ++n2)
                acc[m][n2] = __builtin_amdgcn_mfma_f32_16x16x32_bf16(a, b[n2][kb], acc[m][n2], 0, 0, 0);
        }
    }

    __syncthreads();                         // as[] reuse as C-staging
    u16* cs = as;
#pragma unroll
    for (int m = 0; m < 4; ++m) {
        int rb = m * 16 + (lane >> 4) * 4;
#pragma unroll
        for (int n2 = 0; n2 < 2; ++n2) {
            int col = wave * 32 + n2 * 16 + l16;
#pragma unroll
            for (int r = 0; r < 4; ++r)
                cs[(rb + r) * 128 + col] = bf16_1(acc[m][n2][r]);
        }
    }
    __syncthreads();
#pragma unroll
    for (int i = 0; i < 4; ++i) {
        int idx = tid + i * 256;             // 1024 octs: row=idx>>4, oct=(idx&15)
        int r = idx >> 4;
        int q = (idx & 15) * 8;
        if (row0 + r < n)
            *reinterpret_cast<uint4e*>(out + (size_t)(row0 + r) * 128 + q) =
                *reinterpret_cast<const uint4e*>(&cs[r * 128 + q]);
    }
}

// Full-wave gather with on-the-fly norm: esort = u16 src; w = dis[s]*dis[v].
// Lane owns dims 2*lane..2*lane+1, 8 edges in flight.
__device__ __forceinline__ void gather_accum(const uint* __restrict__ xw,
        const u16* __restrict__ esort, const float* __restrict__ dis,
        int v, int lane, int beg, int end, float& ax, float& ay) {
    float dv = dis[v];
    int e = beg;
    for (; e + 7 < end; e += 8) {
        int sidx[8];
        uint vv[8];
        float wd[8];
#pragma unroll
        for (int j = 0; j < 8; ++j) sidx[j] = esort[e + j];
#pragma unroll
        for (int j = 0; j < 8; ++j) {
            vv[j] = xw[(size_t)sidx[j] * 64 + lane];
            wd[j] = dis[sidx[j]];
        }
#pragma unroll
        for (int j = 0; j < 8; ++j) {
            float w = wd[j] * dv;
            ax += w * bf_lo(vv[j]);
            ay += w * bf_hi(vv[j]);
        }
    }
    for (; e + 1 < end; e += 2) {
        int s0 = esort[e];
        int s1 = esort[e + 1];
        uint v0 = xw[(size_t)s0 * 64 + lane];
        uint v1 = xw[(size_t)s1 * 64 + lane];
        float w0 = dis[s0] * dv, w1 = dis[s1] * dv;
        ax += w0 * bf_lo(v0); ay += w0 * bf_hi(v0);
        ax += w1 * bf_lo(v1); ay += w1 * bf_hi(v1);
    }
    if (e < end) {
        int s0 = esort[e];
        uint v0 = xw[(size_t)s0 * 64 + lane];
        float w0 = dis[s0] * dv;
        ax += w0 * bf_lo(v0); ay += w0 * bf_hi(v0);
    }
    float wv = dv * dv;                            // self-loop norm
    uint vs = xw[(size_t)v * 64 + lane];
    ax += wv * bf_lo(vs); ay += wv * bf_hi(vs);
}

// Pass A: z[v] = packed bf16 of relu(Agg(x@W1)[v] + b1) @ W23  (5 x u32/node).
__global__ __launch_bounds__(256) void agg_proj_kernel(const uint* __restrict__ xw,
        const int* __restrict__ row_ptr, const u16* __restrict__ esort,
        const float* __restrict__ dis, const float* __restrict__ b1,
        const float* __restrict__ W23, uint* __restrict__ z, int n) {
    int v = (int)((blockIdx.x * blockDim.x + threadIdx.x) >> 6);
    int lane = threadIdx.x & 63;
    if (v >= n) return;
    float ax = 0.f, ay = 0.f;
    gather_accum(xw, esort, dis, v, lane, row_ptr[v], row_ptr[v + 1], ax, ay);
    ax = fmaxf(ax + b1[lane * 2], 0.f);
    ay = fmaxf(ay + b1[lane * 2 + 1], 0.f);
    const float* w0 = W23 + (size_t)lane * 20;     // this lane's 2 rows of W23
    float p[10];
#pragma unroll
    for (int c = 0; c < 10; ++c) p[c] = ax * w0[c] + ay * w0[10 + c];
#pragma unroll
    for (int c = 0; c < 10; ++c) {
#pragma unroll
        for (int d = 1; d < 64; d <<= 1) p[c] += __shfl_xor(p[c], d);
    }
    if (lane < 5) z[(size_t)v * 5 + lane] = pack_bf2(p[2 * lane], p[2 * lane + 1]);
}

// Pass B/C: 10-dim aggregation over packed-bf16 z. 4 nodes per wave (16-lane
// groups); lanes 0-4 of each group own dims (2gl, 2gl+1). 8 edges in flight.
// FINAL=0: zout(packed) = Agg(zin).
// FINAL=1: out(f32) = log_softmax(Agg(zin) + s*b23 + b3).
template <int FINAL>
__global__ __launch_bounds__(256) void agg10_kernel(const uint* __restrict__ zin,
        const int* __restrict__ row_ptr, const u16* __restrict__ esort,
        const float* __restrict__ dis, const float* __restrict__ b23,
        const float* __restrict__ b3, void* __restrict__ zout, int n) {
    int wid = (int)((blockIdx.x * blockDim.x + threadIdx.x) >> 6);
    int lane = threadIdx.x & 63;
    int grp = lane >> 4, gl = lane & 15;
    int v = wid * 4 + grp;
    bool act = (v < n);
    bool dl = (gl < 5);
    int beg = act ? row_ptr[v] : 0;
    int end = act ? row_ptr[v + 1] : 0;
    float dv = act ? dis[v] : 0.f;
    float ax = 0.f, ay = 0.f, sw = 0.f;
    int e = beg;
    for (; e + 7 < end; e += 8) {
        int sidx[8];
        uint zz[8];
        float wd[8];
#pragma unroll
        for (int j = 0; j < 8; ++j) sidx[j] = esort[e + j];
#pragma unroll
        for (int j = 0; j < 8; ++j) {
            zz[j] = dl ? zin[(size_t)sidx[j] * 5 + gl] : 0u;
            wd[j] = dis[sidx[j]];
        }
#pragma unroll
        for (int j = 0; j < 8; ++j) {
            float w = wd[j] * dv;
            ax += w * bf_lo(zz[j]);
            ay += w * bf_hi(zz[j]);
            sw += w;
        }
    }
    for (; e < end; ++e) {
        int s0 = esort[e];
        uint z0 = dl ? zin[(size_t)s0 * 5 + gl] : 0u;
        float w0 = dis[s0] * dv;
        ax += w0 * bf_lo(z0);
        ay += w0 * bf_hi(z0);
        sw += w0;
    }
    if (act) {
        float wv = dv * dv;                        // self-loop
        uint zs = dl ? zin[(size_t)v * 5 + gl] : 0u;
        ax += wv * bf_lo(zs);
        ay += wv * bf_hi(zs);
        sw += wv;
    }
    if (FINAL == 0) {
        if (act && dl) ((uint*)zout)[(size_t)v * 5 + gl] = pack_bf2(ax, ay);
    } else {
        float pa = 0.f, pb = 0.f;
        if (dl) {
            pa = ax + sw * b23[2 * gl] + b3[2 * gl];
            pb = ay + sw * b23[2 * gl + 1] + b3[2 * gl + 1];
        }
        float m = dl ? fmaxf(pa, pb) : -3.4e38f;
#pragma unroll
        for (int mask = 1; mask < 16; mask <<= 1) m = fmaxf(m, __shfl_xor(m, mask));
        float s = dl ? (__expf(pa - m) + __expf(pb - m)) : 0.f;
#pragma unroll
        for (int mask = 1; mask < 16; mask <<= 1) s += __shfl_xor(s, mask);
        float ls = __logf(s);
        if (act && dl) {
            float2e o = {pa - m - ls, pb - m - ls};
            *reinterpret_cast<float2e*>((float*)zout + (size_t)v * 10 + 2 * gl) = o;
        }
    }
}

extern "C" void kernel_launch(void* const* d_in, const int* in_sizes, int n_in,
                              void* d_out, int out_size, void* d_ws, size_t ws_size,
                              hipStream_t stream) {
    const float* x  = (const float*)d_in[0];
    const int*   ei = (const int*)d_in[1];   // [2][E] int32
    const float* W1 = (const float*)d_in[2];
    const float* b1 = (const float*)d_in[3];
    const float* W2 = (const float*)d_in[4];
    const float* b2 = (const float*)d_in[5];
    const float* W3 = (const float*)d_in[6];
    const float* b3 = (const float*)d_in[7];
    int N = in_sizes[0] / 128;   // 50000 < 65536: node ids fit u16 (required!)
    int E = in_sizes[1] / 2;
    int NBKT = (N + 255) >> 8;    // 196 for N=50000 (must be <= 256)
    const int NCA = 256;          // chunk blocks for passes A/B

    char* ws = (char*)d_ws;
    size_t off = 0;
    auto alloc = [&](size_t bytes) -> char* {
        char* p = ws + off;
        off = (off + bytes + 255) & ~(size_t)255;
        return p;
    };
    int*   cntA    = (int*)alloc((size_t)NBKT * NCA * 4);  // (bucket x block) counts
    int*   btot    = (int*)alloc(256 * 4);
    int*   row_ptr = (int*)alloc(((size_t)N + 1) * 4);
    float* dis     = (float*)alloc((size_t)N * 4);
    u16*   Wt1     = (u16*)alloc(128 * 128 * 2);
    float* W23     = (float*)alloc(128 * 10 * 4);
    float* b23     = (float*)alloc(10 * 4);
    uint*  ebkt    = (uint*)alloc((size_t)E * 4);          // bucket-sorted dst<<16|src
    u16*   esort   = (u16*)alloc((size_t)E * 2);           // dst-sorted src only
    uint*  bufA    = (uint*)alloc((size_t)N * 64 * 4);     // bf16x2 packed x@W1
    uint*  z       = (uint*)alloc((size_t)N * 5 * 4);      // packed bf16 h1@W23 (1MB)
    uint*  z2      = (uint*)alloc((size_t)N * 5 * 4);      // packed bf16 Agg(z)

    // --- preprocessing: LDS-atomic counting sort + weight prep (no memset) ---
    passA_wt<<<NCA + 6, 256, 0, stream>>>(ei, E, cntA, NBKT, NCA, W1, W2, W3, b2,
                                          Wt1, W23, b23);
    // layer-1 GEMM (needs Wt1 from passA_wt)
    gemm_mfma<<<(N + 63) / 64, 256, 0, stream>>>(x, Wt1, (u16*)bufA, N);
    scan1<<<NBKT, 256, 0, stream>>>(cntA, NCA, btot);
    passB<<<NCA, 256, 0, stream>>>(ei, E, cntA, NCA, NBKT, btot, ebkt);
    passC<<<NBKT, 256, 0, stream>>>(ebkt, btot, esort, row_ptr, dis, N, NBKT, E);
    // --- the single 128-dim gather, fused with ReLU+projection ---
    agg_proj_kernel<<<(N + 3) / 4, 256, 0, stream>>>(bufA, row_ptr, esort, dis, b1, W23, z, N);
    // --- layers 2+3: two 10-dim aggregations (packed bf16, L2-resident) ---
    agg10_kernel<0><<<(N + 15) / 16, 256, 0, stream>>>(z, row_ptr, esort, dis, nullptr, nullptr, z2, N);
    agg10_kernel<1><<<(N + 15) / 16, 256, 0, stream>>>(z2, row_ptr, esort, dis, b23, b3, d_out, N);
}